// Round 12
// baseline (292.317 us; speedup 1.0000x reference)
//
#include <hip/hip_runtime.h>

typedef unsigned short ushort_t;
typedef __attribute__((ext_vector_type(8))) unsigned short ushort8;
typedef __attribute__((ext_vector_type(4))) unsigned short ushort4v;
typedef __attribute__((ext_vector_type(2))) unsigned int uint2v;
typedef __attribute__((ext_vector_type(4))) float f32x4;
typedef __attribute__((ext_vector_type(8))) __bf16 bf16x8;

#define DEVFN static __device__ __forceinline__

DEVFN unsigned short f2bf(float f) {
    unsigned int u = __builtin_bit_cast(unsigned int, f);
    u += 0x7FFFu + ((u >> 16) & 1u);   // round-to-nearest-even
    return (unsigned short)(u >> 16);
}

DEVFN bf16x8 ldsfrag(const ushort_t* p) {
    ushort8 u = *reinterpret_cast<const ushort8*>(p);
    return __builtin_bit_cast(bf16x8, u);
}

DEVFN bf16x8 ldg8(const ushort_t* p) {
    ushort8 u = *reinterpret_cast<const ushort8*>(p);
    return __builtin_bit_cast(bf16x8, u);
}

DEVFN f32x4 mfma16(bf16x8 a, bf16x8 b, f32x4 c) {
    return __builtin_amdgcn_mfma_f32_16x16x32_bf16(a, b, c, 0, 0, 0);
}

// async global -> LDS, 16B per lane; LDS base must be wave-uniform (HW adds lane*16)
DEVFN void gl2lds16(const ushort_t* g, ushort_t* l) {
    __builtin_amdgcn_global_load_lds(
        (const __attribute__((address_space(1))) unsigned int*)g,
        (__attribute__((address_space(3))) unsigned int*)l, 16, 0, 0);
}

DEVFN unsigned int cvtpk(float lo, float hi) {
    unsigned int r;
    asm("v_cvt_pk_bf16_f32 %0, %1, %2" : "=v"(r) : "v"(lo), "v"(hi));
    return r;
}

// tanh-based GELU (exp2/rcp): |gelu_tanh - gelu_erf| below bf16 rounding of h
DEVFN float gelu_fast(float v) {
    const float a = 0.7978845608f * v * fmaf(0.044715f, v * v, 1.0f);
    const float e = __builtin_amdgcn_exp2f(2.885390082f * a);   // e^{2a}
    const float th = 1.0f - 2.0f * __builtin_amdgcn_rcpf(e + 1.0f);
    return 0.5f * v * (1.0f + th);
}

// ---------------------------------------------------------------------------
// Prep: fused weight transpose/convert (blocks 0..6911) + LN1 (blocks 6912+).
// ---------------------------------------------------------------------------
__global__ __launch_bounds__(256) void prep_kernel(
    const float* __restrict__ qkv_w, const float* __restrict__ proj_w,
    const float* __restrict__ fc1_w, const float* __restrict__ fc2_w,
    ushort_t* __restrict__ qkv_wt, ushort_t* __restrict__ proj_wt,
    ushort_t* __restrict__ fc1_wt, ushort_t* __restrict__ fc2_wt,
    const float* __restrict__ x, const float* __restrict__ ln1_g,
    const float* __restrict__ ln1_b, ushort_t* __restrict__ xb) {
    __shared__ float t[32][33];
    const int bid = blockIdx.x;
    const int tid = threadIdx.x;

    if (bid >= 6912) {                     // ---- LN1 on row bid-6912 ----
        const int row = bid - 6912;
        const float* xr = x + (size_t)row * 768;
        float v0 = xr[tid], v1 = xr[tid + 256], v2 = xr[tid + 512];
        float s = v0 + v1 + v2;
        float q = v0 * v0 + v1 * v1 + v2 * v2;
        for (int d = 32; d; d >>= 1) {
            s += __shfl_down(s, d);
            q += __shfl_down(q, d);
        }
        float* red = &t[0][0];
        const int w = tid >> 6, lane = tid & 63;
        if (lane == 0) { red[w] = s; red[4 + w] = q; }
        __syncthreads();
        if (tid == 0) {
            float ts = red[0] + red[1] + red[2] + red[3];
            float tq = red[4] + red[5] + red[6] + red[7];
            float mu = ts * (1.0f / 768.0f);
            float var = tq * (1.0f / 768.0f) - mu * mu;
            red[0] = mu;
            red[1] = rsqrtf(var + 1e-5f);
        }
        __syncthreads();
        const float mu = red[0], rs = red[1];
        ushort_t* orow = xb + (size_t)row * 768;
        orow[tid]       = f2bf((v0 - mu) * rs * ln1_g[tid]       + ln1_b[tid]);
        orow[tid + 256] = f2bf((v1 - mu) * rs * ln1_g[tid + 256] + ln1_b[tid + 256]);
        orow[tid + 512] = f2bf((v2 - mu) * rs * ln1_g[tid + 512] + ln1_b[tid + 512]);
        return;
    }

    // ---- weight transpose tile ----
    const float* in; ushort_t* out; int K, N, n0, k0;
    if (bid < 1728)      { in = qkv_w;  out = qkv_wt;  K = 768;  N = 2304;
                           n0 = (bid % 72) * 32;  k0 = (bid / 72) * 32; }
    else if (bid < 2304) { const int r = bid - 1728; in = proj_w; out = proj_wt;
                           K = 768;  N = 768;
                           n0 = (r % 24) * 32;    k0 = (r / 24) * 32; }
    else if (bid < 4608) { const int r = bid - 2304; in = fc1_w;  out = fc1_wt;
                           K = 768;  N = 3072;
                           n0 = (r % 96) * 32;    k0 = (r / 96) * 32; }
    else                 { const int r = bid - 4608; in = fc2_w;  out = fc2_wt;
                           K = 3072; N = 768;
                           n0 = (r % 24) * 32;    k0 = (r / 24) * 32; }
    const int tx = tid & 31, ty = tid >> 5;  // ty 0..7
    for (int j = 0; j < 4; j++)
        t[ty + 8 * j][tx] = in[(size_t)(k0 + ty + 8 * j) * N + n0 + tx];
    __syncthreads();
    for (int j = 0; j < 4; j++)
        out[(size_t)(n0 + ty + 8 * j) * K + k0 + tx] = f2bf(t[tx][ty + 8 * j]);
}

// ---------------------------------------------------------------------------
// LayerNorm: fp32 [rows,768] -> bf16 [rows,768]   (block = 256 thr, 3 el/thr)
// ---------------------------------------------------------------------------
__global__ __launch_bounds__(256) void ln_kernel(const float* __restrict__ x,
                                                 const float* __restrict__ g,
                                                 const float* __restrict__ bta,
                                                 ushort_t* __restrict__ out) {
    const int row = blockIdx.x;
    const int tid = threadIdx.x;
    const float* xr = x + (size_t)row * 768;
    float v0 = xr[tid], v1 = xr[tid + 256], v2 = xr[tid + 512];
    float s = v0 + v1 + v2;
    float q = v0 * v0 + v1 * v1 + v2 * v2;
    for (int d = 32; d; d >>= 1) {
        s += __shfl_down(s, d);
        q += __shfl_down(q, d);
    }
    __shared__ float red[8];
    const int w = tid >> 6, lane = tid & 63;
    if (lane == 0) { red[w] = s; red[4 + w] = q; }
    __syncthreads();
    if (tid == 0) {
        float ts = red[0] + red[1] + red[2] + red[3];
        float tq = red[4] + red[5] + red[6] + red[7];
        float mu = ts * (1.0f / 768.0f);
        float var = tq * (1.0f / 768.0f) - mu * mu;
        red[0] = mu;
        red[1] = rsqrtf(var + 1e-5f);
    }
    __syncthreads();
    const float mu = red[0], rs = red[1];
    ushort_t* orow = out + (size_t)row * 768;
    orow[tid]       = f2bf((v0 - mu) * rs * g[tid]       + bta[tid]);
    orow[tid + 256] = f2bf((v1 - mu) * rs * g[tid + 256] + bta[tid + 256]);
    orow[tid + 512] = f2bf((v2 - mu) * rs * g[tid + 512] + bta[tid + 512]);
}

// ---------------------------------------------------------------------------
// GEMM: C[M,N] = A[M,K](bf16) @ BT[N,K](bf16)^T + bias, fused epilogues.
// tile 128xBN, 4 waves, swapped-operand mfma (vector epilogue).
// 2-phase async pipeline (r10-proven): STAGE(next) -> compute(cur) -> barrier.
// Double-buffered XOR-swizzled LDS, coalesced pre-swizzled source.
// 1-D grid with XCD-chunked (bn,bm) mapping (L2 A-panel reuse).
// ---------------------------------------------------------------------------
enum { EPI_QKV = 0, EPI_RES = 1, EPI_GELU = 2 };

template <int EPI, int BN, int BK>
__global__ __launch_bounds__(256) void gemm_kernel(
    const ushort_t* __restrict__ A, const ushort_t* __restrict__ BT,
    const float* __restrict__ bias, const float* __restrict__ resid,
    float* __restrict__ outf, ushort_t* __restrict__ outb,
    ushort_t* __restrict__ vtout, int M, int N, int K) {
    constexpr int NT = BN / 32;            // acc N-tiles per wave
    constexpr int SL = BK / 8;             // 16B slots per LDS row
    constexpr int SM = SL - 1;             // swizzle mask
    constexpr int RPI = 64 / SL;           // rows per gload_lds inst
    constexpr int AI = 128 / RPI / 4;      // A staging insts per wave
    constexpr int BI = BN / RPI / 4;       // B staging insts per wave
    __shared__ __align__(16) ushort_t As[2][128 * BK];
    __shared__ __align__(16) ushort_t Bs[2][BN * BK];
    // XCD-chunked block mapping (8 XCDs, 64 bm blocks -> 8 per XCD)
    const int id = blockIdx.x;
    const int nbn = gridDim.x >> 6;
    const int p = id >> 3;
    const int bn = p % nbn;
    const int bm = (id & 7) * 8 + p / nbn;
    const int tid = threadIdx.x;
    const int lane = tid & 63, w = tid >> 6;
    const int wm = (w >> 1) * 64, wn = (w & 1) * (BN / 2);
    const int l15 = lane & 15, l4 = lane >> 4;

    // staging geometry: pre-swizzled global source, linear LDS dest
    const int srow = lane / SL;
    const int scol = ((lane & SM) ^ (srow & SM)) * 8;
    const ushort_t* gA = A + (size_t)(bm * 128 + w * (AI * RPI) + srow) * K + scol;
    const ushort_t* gB = BT + (size_t)(bn * BN + w * (BI * RPI) + srow) * K + scol;

    // hoisted lane-constant fragment-read bases
    const int swm = l15 & SM;
    int aoff[BK / 32], boff[BK / 32];
#pragma unroll
    for (int kk = 0; kk < BK / 32; kk++) {
        aoff[kk] = (wm + l15) * BK + ((((kk << 2) | l4) ^ swm) * 8);
        boff[kk] = (wn + l15) * BK + ((((kk << 2) | l4) ^ swm) * 8);
    }

    f32x4 acc[4][NT] = {};

    auto stage = [&](int k0, int buf) {
#pragma unroll
        for (int i = 0; i < AI; i++)
            gl2lds16(gA + k0 + i * RPI * K, &As[buf][(w * AI + i) * 512]);
#pragma unroll
        for (int i = 0; i < BI; i++)
            gl2lds16(gB + k0 + i * RPI * K, &Bs[buf][(w * BI + i) * 512]);
    };

    stage(0, 0);
    __syncthreads();
    int cur = 0;
    for (int k0 = 0; k0 < K; k0 += BK) {
        if (k0 + BK < K) stage(k0 + BK, cur ^ 1);   // async; drains at barrier
#pragma unroll
        for (int kk = 0; kk < BK / 32; kk++) {
            bf16x8 af[4], bfr[NT];
#pragma unroll
            for (int mt = 0; mt < 4; mt++)
                af[mt] = ldsfrag(As[cur] + aoff[kk] + mt * 16 * BK);
#pragma unroll
            for (int nt = 0; nt < NT; nt++)
                bfr[nt] = ldsfrag(Bs[cur] + boff[kk] + nt * 16 * BK);
#pragma unroll
            for (int mt = 0; mt < 4; mt++)
#pragma unroll
                for (int nt = 0; nt < NT; nt++)
                    acc[mt][nt] = mfma16(bfr[nt], af[mt], acc[mt][nt]);   // swapped
        }
        __syncthreads();   // own stage-loads drained (vmcnt 0) + all waves done
        cur ^= 1;
    }

    // epilogue (swapped D): lane holds C[gr = ..+l15][gc0..gc0+3], gc0 = ..+l4*4
#pragma unroll
    for (int nt = 0; nt < NT; nt++) {
        const int gc0 = bn * BN + wn + nt * 16 + l4 * 4;
        const f32x4 bi = *reinterpret_cast<const f32x4*>(bias + gc0);
#pragma unroll
        for (int mt = 0; mt < 4; mt++) {
            const int gr = bm * 128 + wm + mt * 16 + l15;
            f32x4 v = acc[mt][nt] + bi;
            if constexpr (EPI == EPI_QKV) {
                if (gc0 < 768) v *= 0.18033688011f;    // q * 0.125 * log2(e)
                if (gc0 >= 1536) {                     // V: write transposed to vt
                    const int d = gc0 - 1536;
                    const int h = d >> 6, dh = d & 63;
                    const int b = gr >> 11, tl = gr & 2047;
                    ushort_t* vrow = vtout + ((size_t)((b * 12 + h) * 64 + dh)) * 2048 + tl;
                    vrow[0]        = f2bf(v[0]);
                    vrow[2048]     = f2bf(v[1]);
                    vrow[2 * 2048] = f2bf(v[2]);
                    vrow[3 * 2048] = f2bf(v[3]);
                } else {
                    uint2v o;
                    o[0] = cvtpk(v[0], v[1]);
                    o[1] = cvtpk(v[2], v[3]);
                    *reinterpret_cast<uint2v*>(outb + (size_t)gr * N + gc0) = o;
                }
            } else if constexpr (EPI == EPI_RES) {
                const f32x4 rsd = *reinterpret_cast<const f32x4*>(resid + (size_t)gr * N + gc0);
                *reinterpret_cast<f32x4*>(outf + (size_t)gr * N + gc0) = v + rsd;
            } else {  // EPI_GELU (tanh form, sub-bf16-rounding vs exact erf)
                f32x4 gl;
#pragma unroll
                for (int r = 0; r < 4; r++) gl[r] = gelu_fast(v[r]);
                uint2v o;
                o[0] = cvtpk(gl[0], gl[1]);
                o[1] = cvtpk(gl[2], gl[3]);
                *reinterpret_cast<uint2v*>(outb + (size_t)gr * N + gc0) = o;
            }
        }
    }
}

// ---------------------------------------------------------------------------
// Flash attention, swapped-operand, static-shift softmax, TWO q-tiles/wave.
// Grid 768 1-D (XCD-chunked). Block 256 (4 waves). KV tile 64, double-
// buffered async LDS; K/V fragment reads shared by both q-tiles.
// LDS = 48 KB -> 3 blocks/CU. (r10-proven: 70.1 us)
// ---------------------------------------------------------------------------
__global__ __launch_bounds__(256, 3) void attn_kernel(const ushort_t* __restrict__ qkv,
                                                      const ushort_t* __restrict__ vt,
                                                      ushort_t* __restrict__ out) {
    __shared__ __align__(16) ushort_t Kb[2][4096];      // [kv 64][d 64] slot-swizzled
    __shared__ __align__(16) ushort_t Vb[2][4096];      // [d 64][kv 64] slot-swizzled
    __shared__ __align__(16) ushort_t Ps[4][2][1024];   // per-wave, per-q-tile

    const int bid = blockIdx.x;
    const int nid = (bid & 7) * 96 + (bid >> 3);
    const int qt = nid & 15;    // 0..15 (128 q-rows each)
    const int bh = nid >> 4;    // 0..47
    const int b = bh / 12, h = bh % 12;
    const int tid = threadIdx.x;
    const int lane = tid & 63, w = tid >> 6;
    const int l15 = lane & 15, l4 = lane >> 4;

    // Q fragments for both tiles (lane: q-row = l15, k-slice = l4*8..)
    const ushort_t* qrowA = qkv + (size_t)(b * 2048 + qt * 128 + w * 16 + l15) * 2304 + h * 64;
    const ushort_t* qrowB = qrowA + (size_t)64 * 2304;
    const bf16x8 aqA0 = ldg8(qrowA + l4 * 8);
    const bf16x8 aqA1 = ldg8(qrowA + 32 + l4 * 8);
    const bf16x8 aqB0 = ldg8(qrowB + l4 * 8);
    const bf16x8 aqB1 = ldg8(qrowB + 32 + l4 * 8);

    // staging source (pre-swizzled global, linear LDS dest)
    const int jr0 = w * 16 + (lane >> 3);
    const int jr1 = jr0 + 8;
    const int c0 = ((lane & 7) ^ (jr0 & 7)) * 8;
    const int c1 = ((lane & 7) ^ (jr1 & 7)) * 8;
    const ushort_t* kg0 = qkv + (size_t)(b * 2048 + jr0) * 2304 + 768 + h * 64 + c0;
    const ushort_t* kg1 = qkv + (size_t)(b * 2048 + jr1) * 2304 + 768 + h * 64 + c1;
    const ushort_t* vg0 = vt + (size_t)(bh * 64 + jr0) * 2048 + c0;
    const ushort_t* vg1 = vt + (size_t)(bh * 64 + jr1) * 2048 + c1;

    // hoisted lane-constant LDS read bases
    const int sw7 = l15 & 7;
    const int ka0 = l15 * 64 + ((l4 ^ sw7) * 8);
    const int ka1 = l15 * 64 + (((4 + l4) ^ sw7) * 8);

    // Ps offsets: slot s (8B units) at phys s^(l15&14); row stride 64 ushorts
    ushort_t* const psA = Ps[w][0];
    ushort_t* const psB = Ps[w][1];
    const int pw_m = l15 & 14;
    int pwoff[4];
#pragma unroll
    for (int jt = 0; jt < 4; jt++) pwoff[jt] = l15 * 64 + (((jt * 4 + l4) ^ pw_m) * 4);
    const int pr0 = l15 * 64 + (((2 * l4) ^ pw_m) * 4);
    const int pr1 = l15 * 64 + (((8 + 2 * l4) ^ pw_m) * 4);

    float lrunA = 0.f, lrunB = 0.f;
    f32x4 oaccA[4] = {}, oaccB[4] = {};

    // prologue: stage tile 0 into buf 0
    gl2lds16(kg0, &Kb[0][w * 1024]);
    gl2lds16(kg1, &Kb[0][w * 1024 + 512]);
    gl2lds16(vg0, &Vb[0][w * 1024]);
    gl2lds16(vg1, &Vb[0][w * 1024 + 512]);
    __syncthreads();

    for (int kt = 0; kt < 32; kt++) {
        const int cur = kt & 1;
        if (kt < 31) {   // async prefetch next tile; drains at end-of-loop barrier
            const size_t ko = (size_t)(kt + 1) * 64 * 2304;
            const int vo = (kt + 1) * 64;
            gl2lds16(kg0 + ko, &Kb[cur ^ 1][w * 1024]);
            gl2lds16(kg1 + ko, &Kb[cur ^ 1][w * 1024 + 512]);
            gl2lds16(vg0 + vo, &Vb[cur ^ 1][w * 1024]);
            gl2lds16(vg1 + vo, &Vb[cur ^ 1][w * 1024 + 512]);
        }
        const ushort_t* kb = Kb[cur];
        const ushort_t* vb = Vb[cur];

        // S^T = K @ Q^T for both q-tiles; K fragments shared
        f32x4 stA[4], stB[4];
        __builtin_amdgcn_s_setprio(1);
#pragma unroll
        for (int jt = 0; jt < 4; jt++) {
            const bf16x8 kf0 = ldsfrag(kb + ka0 + jt * 1024);
            const bf16x8 kf1 = ldsfrag(kb + ka1 + jt * 1024);
            f32x4 zA = {}, zB = {};
            zA = mfma16(kf0, aqA0, zA);
            zB = mfma16(kf0, aqB0, zB);
            zA = mfma16(kf1, aqA1, zA);
            zB = mfma16(kf1, aqB1, zB);
            stA[jt] = zA;
            stB[jt] = zB;
        }
        __builtin_amdgcn_s_setprio(0);

        // static-shift softmax for both tiles (independent VALU chains)
        float rsA = 0.f, rsB = 0.f;
#pragma unroll
        for (int jt = 0; jt < 4; jt++) {
            const float a0 = __builtin_amdgcn_exp2f(stA[jt][0]);
            const float a1 = __builtin_amdgcn_exp2f(stA[jt][1]);
            const float a2 = __builtin_amdgcn_exp2f(stA[jt][2]);
            const float a3 = __builtin_amdgcn_exp2f(stA[jt][3]);
            rsA += (a0 + a1) + (a2 + a3);
            uint2v pwA;
            pwA[0] = cvtpk(a0, a1);
            pwA[1] = cvtpk(a2, a3);
            *reinterpret_cast<uint2v*>(psA + pwoff[jt]) = pwA;
            const float b0 = __builtin_amdgcn_exp2f(stB[jt][0]);
            const float b1 = __builtin_amdgcn_exp2f(stB[jt][1]);
            const float b2 = __builtin_amdgcn_exp2f(stB[jt][2]);
            const float b3 = __builtin_amdgcn_exp2f(stB[jt][3]);
            rsB += (b0 + b1) + (b2 + b3);
            uint2v pwB;
            pwB[0] = cvtpk(b0, b1);
            pwB[1] = cvtpk(b2, b3);
            *reinterpret_cast<uint2v*>(psB + pwoff[jt]) = pwB;
        }
        lrunA += rsA;
        lrunB += rsB;

        const bf16x8 pfA0 = ldsfrag(psA + pr0);
        const bf16x8 pfA1 = ldsfrag(psA + pr1);
        const bf16x8 pfB0 = ldsfrag(psB + pr0);
        const bf16x8 pfB1 = ldsfrag(psB + pr1);

        // O^T += V^T @ P^T for both tiles; V fragments shared
        __builtin_amdgcn_s_setprio(1);
#pragma unroll
        for (int dt = 0; dt < 4; dt++) {
            const bf16x8 vf0 = ldsfrag(vb + ka0 + dt * 1024);
            const bf16x8 vf1 = ldsfrag(vb + ka1 + dt * 1024);
            oaccA[dt] = mfma16(vf0, pfA0, oaccA[dt]);
            oaccB[dt] = mfma16(vf0, pfB0, oaccB[dt]);
            oaccA[dt] = mfma16(vf1, pfA1, oaccA[dt]);
            oaccB[dt] = mfma16(vf1, pfB1, oaccB[dt]);
        }
        __builtin_amdgcn_s_setprio(0);
        __syncthreads();   // next tile staged + all waves done with cur
    }

    // row sums + epilogue for both tiles
    lrunA += __shfl_xor(lrunA, 16);
    lrunA += __shfl_xor(lrunA, 32);
    lrunB += __shfl_xor(lrunB, 16);
    lrunB += __shfl_xor(lrunB, 32);
    const float linvA = __builtin_amdgcn_rcpf(lrunA);
    const float linvB = __builtin_amdgcn_rcpf(lrunB);

    ushort_t* orowA = out + (size_t)(b * 2048 + qt * 128 + w * 16 + l15) * 768 + h * 64 + l4 * 4;
    ushort_t* orowB = orowA + (size_t)64 * 768;
#pragma unroll
    for (int dt = 0; dt < 4; dt++) {
        ushort4v oA, oB;
#pragma unroll
        for (int r = 0; r < 4; r++) {
            oA[r] = f2bf(oaccA[dt][r] * linvA);
            oB[r] = f2bf(oaccB[dt][r] * linvB);
        }
        *reinterpret_cast<ushort4v*>(orowA + dt * 16) = oA;
        *reinterpret_cast<ushort4v*>(orowB + dt * 16) = oB;
    }
}

// ---------------------------------------------------------------------------
extern "C" void kernel_launch(void* const* d_in, const int* in_sizes, int n_in,
                              void* d_out, int out_size, void* d_ws, size_t ws_size,
                              hipStream_t stream) {
    const float* x      = (const float*)d_in[0];
    const float* ln1_g  = (const float*)d_in[1];
    const float* ln1_b  = (const float*)d_in[2];
    const float* qkv_w  = (const float*)d_in[3];
    const float* qkv_b  = (const float*)d_in[4];
    const float* proj_w = (const float*)d_in[5];
    const float* proj_b = (const float*)d_in[6];
    const float* ln2_g  = (const float*)d_in[7];
    const float* ln2_b  = (const float*)d_in[8];
    const float* fc1_w  = (const float*)d_in[9];
    const float* fc1_b  = (const float*)d_in[10];
    const float* fc2_w  = (const float*)d_in[11];
    const float* fc2_b  = (const float*)d_in[12];
    float* out = (float*)d_out;

    char* ws = (char*)d_ws;
    ushort_t* qkv_wt  = (ushort_t*)(ws);              // [2304,768]  3,538,944 B
    ushort_t* proj_wt = (ushort_t*)(ws + 3538944);    // [768,768]   1,179,648 B
    ushort_t* fc1_wt  = (ushort_t*)(ws + 4718592);    // [3072,768]  4,718,592 B
    ushort_t* fc2_wt  = (ushort_t*)(ws + 9437184);    // [768,3072]  4,718,592 B
    ushort_t* xb      = (ushort_t*)(ws + 14155776);   // [8192,768]  12,582,912 B
    ushort_t* aob     = (ushort_t*)(ws + 26738688);   // [8192,768]  12,582,912 B
    ushort_t* qkvb    = (ushort_t*)(ws + 39321600);   // [8192,2304] 37,748,736 B
    ushort_t* vtb     = (ushort_t*)(ws + 77070336);   // [48,64,2048]12,582,912 B
    ushort_t* hb      = (ushort_t*)(ws + 39321600);   // [8192,3072] aliases qkvb+vtb

    dim3 blk(256);

    // fused weight transpose (blocks 0..6911) + LN1 (blocks 6912..15103)
    prep_kernel<<<dim3(15104), blk, 0, stream>>>(qkv_w, proj_w, fc1_w, fc2_w,
                                                 qkv_wt, proj_wt, fc1_wt, fc2_wt,
                                                 x, ln1_g, ln1_b, xb);
    // QKV gemm (q pre-scaled by 0.125*log2e; V written transposed into vtb)
    gemm_kernel<EPI_QKV, 128, 32><<<dim3(18 * 64), blk, 0, stream>>>(
        xb, qkv_wt, qkv_b, nullptr, nullptr, qkvb, vtb, 8192, 2304, 768);
    // flash attention (768 blocks, XCD-chunked internally, 2 q-tiles/block)
    attn_kernel<<<dim3(768), blk, 0, stream>>>(qkvb, vtb, aob);
    // proj + residual -> out (fp32, doubles as x1); BN=64/BK=64 (r10-proven)
    gemm_kernel<EPI_RES, 64, 64><<<dim3(12 * 64), blk, 0, stream>>>(
        aob, proj_wt, proj_b, x, out, nullptr, nullptr, 8192, 768, 768);
    // LN2
    ln_kernel<<<8192, blk, 0, stream>>>(out, ln2_g, ln2_b, xb);
    // FC1 + fast GELU (bf16 out) — EXPERIMENT: 128x256 tile (NT=8)
    gemm_kernel<EPI_GELU, 256, 32><<<dim3(12 * 64), blk, 0, stream>>>(
        xb, fc1_wt, fc1_b, nullptr, nullptr, hb, nullptr, 8192, 3072, 768);
    // FC2 + residual -> out; BN=64/BK=64 (r10-proven)
    gemm_kernel<EPI_RES, 64, 64><<<dim3(12 * 64), blk, 0, stream>>>(
        hb, fc2_wt, fc2_b, out, out, nullptr, nullptr, 8192, 768, 3072);
}

// Round 13
// 268.149 us; speedup vs baseline: 1.0901x; 1.0901x over previous
//
#include <hip/hip_runtime.h>

typedef unsigned short ushort_t;
typedef __attribute__((ext_vector_type(8))) unsigned short ushort8;
typedef __attribute__((ext_vector_type(4))) unsigned short ushort4v;
typedef __attribute__((ext_vector_type(2))) unsigned int uint2v;
typedef __attribute__((ext_vector_type(4))) float f32x4;
typedef __attribute__((ext_vector_type(8))) __bf16 bf16x8;

#define DEVFN static __device__ __forceinline__

DEVFN unsigned short f2bf(float f) {
    unsigned int u = __builtin_bit_cast(unsigned int, f);
    u += 0x7FFFu + ((u >> 16) & 1u);   // round-to-nearest-even
    return (unsigned short)(u >> 16);
}

DEVFN bf16x8 ldsfrag(const ushort_t* p) {
    ushort8 u = *reinterpret_cast<const ushort8*>(p);
    return __builtin_bit_cast(bf16x8, u);
}

DEVFN bf16x8 ldg8(const ushort_t* p) {
    ushort8 u = *reinterpret_cast<const ushort8*>(p);
    return __builtin_bit_cast(bf16x8, u);
}

DEVFN f32x4 mfma16(bf16x8 a, bf16x8 b, f32x4 c) {
    return __builtin_amdgcn_mfma_f32_16x16x32_bf16(a, b, c, 0, 0, 0);
}

// async global -> LDS, 16B per lane; LDS base must be wave-uniform (HW adds lane*16)
DEVFN void gl2lds16(const ushort_t* g, ushort_t* l) {
    __builtin_amdgcn_global_load_lds(
        (const __attribute__((address_space(1))) unsigned int*)g,
        (__attribute__((address_space(3))) unsigned int*)l, 16, 0, 0);
}

DEVFN unsigned int cvtpk(float lo, float hi) {
    unsigned int r;
    asm("v_cvt_pk_bf16_f32 %0, %1, %2" : "=v"(r) : "v"(lo), "v"(hi));
    return r;
}

// tanh-based GELU (exp2/rcp): |gelu_tanh - gelu_erf| below bf16 rounding of h
DEVFN float gelu_fast(float v) {
    const float a = 0.7978845608f * v * fmaf(0.044715f, v * v, 1.0f);
    const float e = __builtin_amdgcn_exp2f(2.885390082f * a);   // e^{2a}
    const float th = 1.0f - 2.0f * __builtin_amdgcn_rcpf(e + 1.0f);
    return 0.5f * v * (1.0f + th);
}

// ---------------------------------------------------------------------------
// Prep: fused weight transpose/convert (blocks 0..6911) + LN1 (blocks 6912+).
// ---------------------------------------------------------------------------
__global__ __launch_bounds__(256) void prep_kernel(
    const float* __restrict__ qkv_w, const float* __restrict__ proj_w,
    const float* __restrict__ fc1_w, const float* __restrict__ fc2_w,
    ushort_t* __restrict__ qkv_wt, ushort_t* __restrict__ proj_wt,
    ushort_t* __restrict__ fc1_wt, ushort_t* __restrict__ fc2_wt,
    const float* __restrict__ x, const float* __restrict__ ln1_g,
    const float* __restrict__ ln1_b, ushort_t* __restrict__ xb) {
    __shared__ float t[32][33];
    const int bid = blockIdx.x;
    const int tid = threadIdx.x;

    if (bid >= 6912) {                     // ---- LN1 on row bid-6912 ----
        const int row = bid - 6912;
        const float* xr = x + (size_t)row * 768;
        float v0 = xr[tid], v1 = xr[tid + 256], v2 = xr[tid + 512];
        float s = v0 + v1 + v2;
        float q = v0 * v0 + v1 * v1 + v2 * v2;
        for (int d = 32; d; d >>= 1) {
            s += __shfl_down(s, d);
            q += __shfl_down(q, d);
        }
        float* red = &t[0][0];
        const int w = tid >> 6, lane = tid & 63;
        if (lane == 0) { red[w] = s; red[4 + w] = q; }
        __syncthreads();
        if (tid == 0) {
            float ts = red[0] + red[1] + red[2] + red[3];
            float tq = red[4] + red[5] + red[6] + red[7];
            float mu = ts * (1.0f / 768.0f);
            float var = tq * (1.0f / 768.0f) - mu * mu;
            red[0] = mu;
            red[1] = rsqrtf(var + 1e-5f);
        }
        __syncthreads();
        const float mu = red[0], rs = red[1];
        ushort_t* orow = xb + (size_t)row * 768;
        orow[tid]       = f2bf((v0 - mu) * rs * ln1_g[tid]       + ln1_b[tid]);
        orow[tid + 256] = f2bf((v1 - mu) * rs * ln1_g[tid + 256] + ln1_b[tid + 256]);
        orow[tid + 512] = f2bf((v2 - mu) * rs * ln1_g[tid + 512] + ln1_b[tid + 512]);
        return;
    }

    // ---- weight transpose tile ----
    const float* in; ushort_t* out; int K, N, n0, k0;
    if (bid < 1728)      { in = qkv_w;  out = qkv_wt;  K = 768;  N = 2304;
                           n0 = (bid % 72) * 32;  k0 = (bid / 72) * 32; }
    else if (bid < 2304) { const int r = bid - 1728; in = proj_w; out = proj_wt;
                           K = 768;  N = 768;
                           n0 = (r % 24) * 32;    k0 = (r / 24) * 32; }
    else if (bid < 4608) { const int r = bid - 2304; in = fc1_w;  out = fc1_wt;
                           K = 768;  N = 3072;
                           n0 = (r % 96) * 32;    k0 = (r / 96) * 32; }
    else                 { const int r = bid - 4608; in = fc2_w;  out = fc2_wt;
                           K = 3072; N = 768;
                           n0 = (r % 24) * 32;    k0 = (r / 24) * 32; }
    const int tx = tid & 31, ty = tid >> 5;  // ty 0..7
    for (int j = 0; j < 4; j++)
        t[ty + 8 * j][tx] = in[(size_t)(k0 + ty + 8 * j) * N + n0 + tx];
    __syncthreads();
    for (int j = 0; j < 4; j++)
        out[(size_t)(n0 + ty + 8 * j) * K + k0 + tx] = f2bf(t[tx][ty + 8 * j]);
}

// ---------------------------------------------------------------------------
// LayerNorm: fp32 [rows,768] -> bf16 [rows,768]   (block = 256 thr, 3 el/thr)
// ---------------------------------------------------------------------------
__global__ __launch_bounds__(256) void ln_kernel(const float* __restrict__ x,
                                                 const float* __restrict__ g,
                                                 const float* __restrict__ bta,
                                                 ushort_t* __restrict__ out) {
    const int row = blockIdx.x;
    const int tid = threadIdx.x;
    const float* xr = x + (size_t)row * 768;
    float v0 = xr[tid], v1 = xr[tid + 256], v2 = xr[tid + 512];
    float s = v0 + v1 + v2;
    float q = v0 * v0 + v1 * v1 + v2 * v2;
    for (int d = 32; d; d >>= 1) {
        s += __shfl_down(s, d);
        q += __shfl_down(q, d);
    }
    __shared__ float red[8];
    const int w = tid >> 6, lane = tid & 63;
    if (lane == 0) { red[w] = s; red[4 + w] = q; }
    __syncthreads();
    if (tid == 0) {
        float ts = red[0] + red[1] + red[2] + red[3];
        float tq = red[4] + red[5] + red[6] + red[7];
        float mu = ts * (1.0f / 768.0f);
        float var = tq * (1.0f / 768.0f) - mu * mu;
        red[0] = mu;
        red[1] = rsqrtf(var + 1e-5f);
    }
    __syncthreads();
    const float mu = red[0], rs = red[1];
    ushort_t* orow = out + (size_t)row * 768;
    orow[tid]       = f2bf((v0 - mu) * rs * g[tid]       + bta[tid]);
    orow[tid + 256] = f2bf((v1 - mu) * rs * g[tid + 256] + bta[tid + 256]);
    orow[tid + 512] = f2bf((v2 - mu) * rs * g[tid + 512] + bta[tid + 512]);
}

// ---------------------------------------------------------------------------
// GEMM: C[M,N] = A[M,K](bf16) @ BT[N,K](bf16)^T + bias, fused epilogues.
// tile 128xBN, 4 waves, swapped-operand mfma (vector epilogue).
// 2-phase async pipeline (r10-proven): STAGE(next) -> compute(cur) -> barrier.
// Double-buffered XOR-swizzled LDS, coalesced pre-swizzled source.
// 1-D grid with XCD-chunked (bn,bm) mapping (L2 A-panel reuse).
// ---------------------------------------------------------------------------
enum { EPI_QKV = 0, EPI_RES = 1, EPI_GELU = 2 };

template <int EPI, int BN, int BK>
__global__ __launch_bounds__(256) void gemm_kernel(
    const ushort_t* __restrict__ A, const ushort_t* __restrict__ BT,
    const float* __restrict__ bias, const float* __restrict__ resid,
    float* __restrict__ outf, ushort_t* __restrict__ outb,
    ushort_t* __restrict__ vtout, int M, int N, int K) {
    constexpr int NT = BN / 32;            // acc N-tiles per wave
    constexpr int SL = BK / 8;             // 16B slots per LDS row
    constexpr int SM = SL - 1;             // swizzle mask
    constexpr int RPI = 64 / SL;           // rows per gload_lds inst
    constexpr int AI = 128 / RPI / 4;      // A staging insts per wave
    constexpr int BI = BN / RPI / 4;       // B staging insts per wave
    __shared__ __align__(16) ushort_t As[2][128 * BK];
    __shared__ __align__(16) ushort_t Bs[2][BN * BK];
    // XCD-chunked block mapping (8 XCDs, 64 bm blocks -> 8 per XCD)
    const int id = blockIdx.x;
    const int nbn = gridDim.x >> 6;
    const int p = id >> 3;
    const int bn = p % nbn;
    const int bm = (id & 7) * 8 + p / nbn;
    const int tid = threadIdx.x;
    const int lane = tid & 63, w = tid >> 6;
    const int wm = (w >> 1) * 64, wn = (w & 1) * (BN / 2);
    const int l15 = lane & 15, l4 = lane >> 4;

    // staging geometry: pre-swizzled global source, linear LDS dest
    const int srow = lane / SL;
    const int scol = ((lane & SM) ^ (srow & SM)) * 8;
    const ushort_t* gA = A + (size_t)(bm * 128 + w * (AI * RPI) + srow) * K + scol;
    const ushort_t* gB = BT + (size_t)(bn * BN + w * (BI * RPI) + srow) * K + scol;

    // hoisted lane-constant fragment-read bases
    const int swm = l15 & SM;
    int aoff[BK / 32], boff[BK / 32];
#pragma unroll
    for (int kk = 0; kk < BK / 32; kk++) {
        aoff[kk] = (wm + l15) * BK + ((((kk << 2) | l4) ^ swm) * 8);
        boff[kk] = (wn + l15) * BK + ((((kk << 2) | l4) ^ swm) * 8);
    }

    f32x4 acc[4][NT] = {};

    auto stage = [&](int k0, int buf) {
#pragma unroll
        for (int i = 0; i < AI; i++)
            gl2lds16(gA + k0 + i * RPI * K, &As[buf][(w * AI + i) * 512]);
#pragma unroll
        for (int i = 0; i < BI; i++)
            gl2lds16(gB + k0 + i * RPI * K, &Bs[buf][(w * BI + i) * 512]);
    };

    stage(0, 0);
    __syncthreads();
    int cur = 0;
    for (int k0 = 0; k0 < K; k0 += BK) {
        if (k0 + BK < K) stage(k0 + BK, cur ^ 1);   // async; drains at barrier
#pragma unroll
        for (int kk = 0; kk < BK / 32; kk++) {
            bf16x8 af[4], bfr[NT];
#pragma unroll
            for (int mt = 0; mt < 4; mt++)
                af[mt] = ldsfrag(As[cur] + aoff[kk] + mt * 16 * BK);
#pragma unroll
            for (int nt = 0; nt < NT; nt++)
                bfr[nt] = ldsfrag(Bs[cur] + boff[kk] + nt * 16 * BK);
#pragma unroll
            for (int mt = 0; mt < 4; mt++)
#pragma unroll
                for (int nt = 0; nt < NT; nt++)
                    acc[mt][nt] = mfma16(bfr[nt], af[mt], acc[mt][nt]);   // swapped
        }
        __syncthreads();   // own stage-loads drained (vmcnt 0) + all waves done
        cur ^= 1;
    }

    // epilogue (swapped D): lane holds C[gr = ..+l15][gc0..gc0+3], gc0 = ..+l4*4
#pragma unroll
    for (int nt = 0; nt < NT; nt++) {
        const int gc0 = bn * BN + wn + nt * 16 + l4 * 4;
        const f32x4 bi = *reinterpret_cast<const f32x4*>(bias + gc0);
#pragma unroll
        for (int mt = 0; mt < 4; mt++) {
            const int gr = bm * 128 + wm + mt * 16 + l15;
            f32x4 v = acc[mt][nt] + bi;
            if constexpr (EPI == EPI_QKV) {
                if (gc0 < 768) v *= 0.18033688011f;    // q * 0.125 * log2(e)
                if (gc0 >= 1536) {                     // V: write transposed to vt
                    const int d = gc0 - 1536;
                    const int h = d >> 6, dh = d & 63;
                    const int b = gr >> 11, tl = gr & 2047;
                    ushort_t* vrow = vtout + ((size_t)((b * 12 + h) * 64 + dh)) * 2048 + tl;
                    vrow[0]        = f2bf(v[0]);
                    vrow[2048]     = f2bf(v[1]);
                    vrow[2 * 2048] = f2bf(v[2]);
                    vrow[3 * 2048] = f2bf(v[3]);
                } else {
                    uint2v o;
                    o[0] = cvtpk(v[0], v[1]);
                    o[1] = cvtpk(v[2], v[3]);
                    *reinterpret_cast<uint2v*>(outb + (size_t)gr * N + gc0) = o;
                }
            } else if constexpr (EPI == EPI_RES) {
                const f32x4 rsd = *reinterpret_cast<const f32x4*>(resid + (size_t)gr * N + gc0);
                *reinterpret_cast<f32x4*>(outf + (size_t)gr * N + gc0) = v + rsd;
            } else {  // EPI_GELU (tanh form, sub-bf16-rounding vs exact erf)
                f32x4 gl;
#pragma unroll
                for (int r = 0; r < 4; r++) gl[r] = gelu_fast(v[r]);
                uint2v o;
                o[0] = cvtpk(gl[0], gl[1]);
                o[1] = cvtpk(gl[2], gl[3]);
                *reinterpret_cast<uint2v*>(outb + (size_t)gr * N + gc0) = o;
            }
        }
    }
}

// ---------------------------------------------------------------------------
// Flash attention, swapped-operand, static-shift softmax, TWO q-tiles/wave.
// Grid 768 1-D (XCD-chunked). Block 256 (4 waves). KV tile 64, double-
// buffered async LDS; K/V fragment reads shared by both q-tiles.
// Single per-wave Ps buffer reused sequentially by the two q-tiles (in-wave
// LDS ordering guarantees A-reads complete before B-writes to same addrs).
// LDS = 36864 B -> 4 blocks/CU.
// ---------------------------------------------------------------------------
__global__ __launch_bounds__(256, 4) void attn_kernel(const ushort_t* __restrict__ qkv,
                                                      const ushort_t* __restrict__ vt,
                                                      ushort_t* __restrict__ out) {
    __shared__ __align__(16) ushort_t Kb[2][4096];      // [kv 64][d 64] slot-swizzled
    __shared__ __align__(16) ushort_t Vb[2][4096];      // [d 64][kv 64] slot-swizzled
    __shared__ __align__(16) ushort_t Ps[4][1024];      // per-wave, time-shared A/B

    const int bid = blockIdx.x;
    const int nid = (bid & 7) * 96 + (bid >> 3);
    const int qt = nid & 15;    // 0..15 (128 q-rows each)
    const int bh = nid >> 4;    // 0..47
    const int b = bh / 12, h = bh % 12;
    const int tid = threadIdx.x;
    const int lane = tid & 63, w = tid >> 6;
    const int l15 = lane & 15, l4 = lane >> 4;

    // Q fragments for both tiles (lane: q-row = l15, k-slice = l4*8..)
    const ushort_t* qrowA = qkv + (size_t)(b * 2048 + qt * 128 + w * 16 + l15) * 2304 + h * 64;
    const ushort_t* qrowB = qrowA + (size_t)64 * 2304;
    const bf16x8 aqA0 = ldg8(qrowA + l4 * 8);
    const bf16x8 aqA1 = ldg8(qrowA + 32 + l4 * 8);
    const bf16x8 aqB0 = ldg8(qrowB + l4 * 8);
    const bf16x8 aqB1 = ldg8(qrowB + 32 + l4 * 8);

    // staging source (pre-swizzled global, linear LDS dest)
    const int jr0 = w * 16 + (lane >> 3);
    const int jr1 = jr0 + 8;
    const int c0 = ((lane & 7) ^ (jr0 & 7)) * 8;
    const int c1 = ((lane & 7) ^ (jr1 & 7)) * 8;
    const ushort_t* kg0 = qkv + (size_t)(b * 2048 + jr0) * 2304 + 768 + h * 64 + c0;
    const ushort_t* kg1 = qkv + (size_t)(b * 2048 + jr1) * 2304 + 768 + h * 64 + c1;
    const ushort_t* vg0 = vt + (size_t)(bh * 64 + jr0) * 2048 + c0;
    const ushort_t* vg1 = vt + (size_t)(bh * 64 + jr1) * 2048 + c1;

    // hoisted lane-constant LDS read bases
    const int sw7 = l15 & 7;
    const int ka0 = l15 * 64 + ((l4 ^ sw7) * 8);
    const int ka1 = l15 * 64 + (((4 + l4) ^ sw7) * 8);

    // Ps offsets: slot s (8B units) at phys s^(l15&14); row stride 64 ushorts
    ushort_t* const psw = Ps[w];
    const int pw_m = l15 & 14;
    int pwoff[4];
#pragma unroll
    for (int jt = 0; jt < 4; jt++) pwoff[jt] = l15 * 64 + (((jt * 4 + l4) ^ pw_m) * 4);
    const int pr0 = l15 * 64 + (((2 * l4) ^ pw_m) * 4);
    const int pr1 = l15 * 64 + (((8 + 2 * l4) ^ pw_m) * 4);

    float lrunA = 0.f, lrunB = 0.f;
    f32x4 oaccA[4] = {}, oaccB[4] = {};

    // prologue: stage tile 0 into buf 0
    gl2lds16(kg0, &Kb[0][w * 1024]);
    gl2lds16(kg1, &Kb[0][w * 1024 + 512]);
    gl2lds16(vg0, &Vb[0][w * 1024]);
    gl2lds16(vg1, &Vb[0][w * 1024 + 512]);
    __syncthreads();

    for (int kt = 0; kt < 32; kt++) {
        const int cur = kt & 1;
        if (kt < 31) {   // async prefetch next tile; drains at end-of-loop barrier
            const size_t ko = (size_t)(kt + 1) * 64 * 2304;
            const int vo = (kt + 1) * 64;
            gl2lds16(kg0 + ko, &Kb[cur ^ 1][w * 1024]);
            gl2lds16(kg1 + ko, &Kb[cur ^ 1][w * 1024 + 512]);
            gl2lds16(vg0 + vo, &Vb[cur ^ 1][w * 1024]);
            gl2lds16(vg1 + vo, &Vb[cur ^ 1][w * 1024 + 512]);
        }
        const ushort_t* kb = Kb[cur];
        const ushort_t* vb = Vb[cur];

        // S^T = K @ Q^T for both q-tiles; K fragments shared
        f32x4 stA[4], stB[4];
        __builtin_amdgcn_s_setprio(1);
#pragma unroll
        for (int jt = 0; jt < 4; jt++) {
            const bf16x8 kf0 = ldsfrag(kb + ka0 + jt * 1024);
            const bf16x8 kf1 = ldsfrag(kb + ka1 + jt * 1024);
            f32x4 zA = {}, zB = {};
            zA = mfma16(kf0, aqA0, zA);
            zB = mfma16(kf0, aqB0, zB);
            zA = mfma16(kf1, aqA1, zA);
            zB = mfma16(kf1, aqB1, zB);
            stA[jt] = zA;
            stB[jt] = zB;
        }
        __builtin_amdgcn_s_setprio(0);

        // static-shift softmax tile A -> Ps -> read pfA (frees Ps for B)
        float rsA = 0.f, rsB = 0.f;
#pragma unroll
        for (int jt = 0; jt < 4; jt++) {
            const float a0 = __builtin_amdgcn_exp2f(stA[jt][0]);
            const float a1 = __builtin_amdgcn_exp2f(stA[jt][1]);
            const float a2 = __builtin_amdgcn_exp2f(stA[jt][2]);
            const float a3 = __builtin_amdgcn_exp2f(stA[jt][3]);
            rsA += (a0 + a1) + (a2 + a3);
            uint2v pwA;
            pwA[0] = cvtpk(a0, a1);
            pwA[1] = cvtpk(a2, a3);
            *reinterpret_cast<uint2v*>(psw + pwoff[jt]) = pwA;
        }
        lrunA += rsA;
        const bf16x8 pfA0 = ldsfrag(psw + pr0);
        const bf16x8 pfA1 = ldsfrag(psw + pr1);

        // softmax tile B -> same Ps (in-wave LDS order: A-reads precede B-writes)
#pragma unroll
        for (int jt = 0; jt < 4; jt++) {
            const float b0 = __builtin_amdgcn_exp2f(stB[jt][0]);
            const float b1 = __builtin_amdgcn_exp2f(stB[jt][1]);
            const float b2 = __builtin_amdgcn_exp2f(stB[jt][2]);
            const float b3 = __builtin_amdgcn_exp2f(stB[jt][3]);
            rsB += (b0 + b1) + (b2 + b3);
            uint2v pwB;
            pwB[0] = cvtpk(b0, b1);
            pwB[1] = cvtpk(b2, b3);
            *reinterpret_cast<uint2v*>(psw + pwoff[jt]) = pwB;
        }
        lrunB += rsB;
        const bf16x8 pfB0 = ldsfrag(psw + pr0);
        const bf16x8 pfB1 = ldsfrag(psw + pr1);

        // O^T += V^T @ P^T for both tiles; V fragments shared
        __builtin_amdgcn_s_setprio(1);
#pragma unroll
        for (int dt = 0; dt < 4; dt++) {
            const bf16x8 vf0 = ldsfrag(vb + ka0 + dt * 1024);
            const bf16x8 vf1 = ldsfrag(vb + ka1 + dt * 1024);
            oaccA[dt] = mfma16(vf0, pfA0, oaccA[dt]);
            oaccB[dt] = mfma16(vf0, pfB0, oaccB[dt]);
            oaccA[dt] = mfma16(vf1, pfA1, oaccA[dt]);
            oaccB[dt] = mfma16(vf1, pfB1, oaccB[dt]);
        }
        __builtin_amdgcn_s_setprio(0);
        __syncthreads();   // next tile staged + all waves done with cur
    }

    // row sums + epilogue for both tiles
    lrunA += __shfl_xor(lrunA, 16);
    lrunA += __shfl_xor(lrunA, 32);
    lrunB += __shfl_xor(lrunB, 16);
    lrunB += __shfl_xor(lrunB, 32);
    const float linvA = __builtin_amdgcn_rcpf(lrunA);
    const float linvB = __builtin_amdgcn_rcpf(lrunB);

    ushort_t* orowA = out + (size_t)(b * 2048 + qt * 128 + w * 16 + l15) * 768 + h * 64 + l4 * 4;
    ushort_t* orowB = orowA + (size_t)64 * 768;
#pragma unroll
    for (int dt = 0; dt < 4; dt++) {
        ushort4v oA, oB;
#pragma unroll
        for (int r = 0; r < 4; r++) {
            oA[r] = f2bf(oaccA[dt][r] * linvA);
            oB[r] = f2bf(oaccB[dt][r] * linvB);
        }
        *reinterpret_cast<ushort4v*>(orowA + dt * 16) = oA;
        *reinterpret_cast<ushort4v*>(orowB + dt * 16) = oB;
    }
}

// ---------------------------------------------------------------------------
extern "C" void kernel_launch(void* const* d_in, const int* in_sizes, int n_in,
                              void* d_out, int out_size, void* d_ws, size_t ws_size,
                              hipStream_t stream) {
    const float* x      = (const float*)d_in[0];
    const float* ln1_g  = (const float*)d_in[1];
    const float* ln1_b  = (const float*)d_in[2];
    const float* qkv_w  = (const float*)d_in[3];
    const float* qkv_b  = (const float*)d_in[4];
    const float* proj_w = (const float*)d_in[5];
    const float* proj_b = (const float*)d_in[6];
    const float* ln2_g  = (const float*)d_in[7];
    const float* ln2_b  = (const float*)d_in[8];
    const float* fc1_w  = (const float*)d_in[9];
    const float* fc1_b  = (const float*)d_in[10];
    const float* fc2_w  = (const float*)d_in[11];
    const float* fc2_b  = (const float*)d_in[12];
    float* out = (float*)d_out;

    char* ws = (char*)d_ws;
    ushort_t* qkv_wt  = (ushort_t*)(ws);              // [2304,768]  3,538,944 B
    ushort_t* proj_wt = (ushort_t*)(ws + 3538944);    // [768,768]   1,179,648 B
    ushort_t* fc1_wt  = (ushort_t*)(ws + 4718592);    // [3072,768]  4,718,592 B
    ushort_t* fc2_wt  = (ushort_t*)(ws + 9437184);    // [768,3072]  4,718,592 B
    ushort_t* xb      = (ushort_t*)(ws + 14155776);   // [8192,768]  12,582,912 B
    ushort_t* aob     = (ushort_t*)(ws + 26738688);   // [8192,768]  12,582,912 B
    ushort_t* qkvb    = (ushort_t*)(ws + 39321600);   // [8192,2304] 37,748,736 B
    ushort_t* vtb     = (ushort_t*)(ws + 77070336);   // [48,64,2048]12,582,912 B
    ushort_t* hb      = (ushort_t*)(ws + 39321600);   // [8192,3072] aliases qkvb+vtb

    dim3 blk(256);

    // fused weight transpose (blocks 0..6911) + LN1 (blocks 6912..15103)
    prep_kernel<<<dim3(15104), blk, 0, stream>>>(qkv_w, proj_w, fc1_w, fc2_w,
                                                 qkv_wt, proj_wt, fc1_wt, fc2_wt,
                                                 x, ln1_g, ln1_b, xb);
    // QKV gemm (q pre-scaled by 0.125*log2e; V written transposed into vtb)
    gemm_kernel<EPI_QKV, 128, 32><<<dim3(18 * 64), blk, 0, stream>>>(
        xb, qkv_wt, qkv_b, nullptr, nullptr, qkvb, vtb, 8192, 2304, 768);
    // flash attention (768 blocks, XCD-chunked internally, 2 q-tiles/block)
    attn_kernel<<<dim3(768), blk, 0, stream>>>(qkvb, vtb, aob);
    // proj + residual -> out (fp32, doubles as x1); BN=64/BK=64 (r10-proven)
    gemm_kernel<EPI_RES, 64, 64><<<dim3(12 * 64), blk, 0, stream>>>(
        aob, proj_wt, proj_b, x, out, nullptr, nullptr, 8192, 768, 768);
    // LN2
    ln_kernel<<<8192, blk, 0, stream>>>(out, ln2_g, ln2_b, xb);
    // FC1 + fast GELU (bf16 out) — r10-proven BN=128/BK=32
    gemm_kernel<EPI_GELU, 128, 32><<<dim3(24 * 64), blk, 0, stream>>>(
        xb, fc1_wt, fc1_b, nullptr, nullptr, hb, nullptr, 8192, 3072, 768);
    // FC2 + residual -> out; BN=64/BK=64 (r10-proven)
    gemm_kernel<EPI_RES, 64, 64><<<dim3(12 * 64), blk, 0, stream>>>(
        hb, fc2_wt, fc2_b, out, out, nullptr, nullptr, 8192, 768, 3072);
}